// Round 12
// baseline (86.942 us; speedup 1.0000x reference)
//
#include <hip/hip_runtime.h>
#include <hip/hip_bf16.h>

#define N_ 4096
#define H_ 16
#define D_ 64
#define G1ROWOFF 65536  // row offset of group-1 region in Kh/Vt (2*8*4096 rows)

typedef __attribute__((ext_vector_type(4))) float f32x4;
typedef __attribute__((ext_vector_type(8))) _Float16 f16x8;

#define AS1 __attribute__((address_space(1)))
#define AS3 __attribute__((address_space(3)))

// Single-instruction pair convert f32x2 -> f16x2 (v_cvt_pkrtz_f16_f32).
__device__ __forceinline__ unsigned int pkrtz(float a, float b){
  auto h = __builtin_amdgcn_cvt_pkrtz(a, b);
  unsigned int r; __builtin_memcpy(&r, &h, 4); return r;
}
__device__ __forceinline__ unsigned int pku(unsigned int lo, unsigned int hi){
  return lo | (hi << 16);
}

// ---------------------------------------------------------------------------
// Hilbert mapping (exact replica of reference incl. its quirks).
// ---------------------------------------------------------------------------
__global__ __launch_bounds__(1024) void hilbert_map_kernel(int* __restrict__ mapping){
  __shared__ int sm[4096];
  const int t = threadIdx.x;
#pragma unroll
  for(int jj=0;jj<4;jj++) mapping[t*4+jj] = 0;   // np.zeros default
  int li_a[4], val_a[4];
#pragma unroll
  for(int jj=0;jj<4;jj++){
    int i = t*4+jj;
    int x=0,y=0,d=i;
#pragma unroll
    for(int s=1;s<64;s<<=1){
      int rx=(d>>1)&1;
      int ry=(d^rx)&1;
      if(ry==0){
        if(rx==1){ x=63-x; y=63-y; }   // nn-1-x reflection (reference quirk)
        int tp=x; x=y; y=tp;
      }
      x+=s*rx; y+=s*ry;
      d>>=2;
    }
    int li=y*64+x;
    li_a[jj]=li;
    val_a[jj]=(li<4096)?1:0;
    sm[i]=val_a[jj];
  }
  __syncthreads();
  for(int off=1;off<4096;off<<=1){
    int v[4];
#pragma unroll
    for(int jj=0;jj<4;jj++){
      int i=t*4+jj;
      v[jj]=sm[i]+((i>=off)?sm[i-off]:0);
    }
    __syncthreads();
#pragma unroll
    for(int jj=0;jj<4;jj++) sm[t*4+jj]=v[jj];
    __syncthreads();
  }
#pragma unroll
  for(int jj=0;jj<4;jj++){
    if(val_a[jj]){
      int rank=sm[t*4+jj]-1;
      int li=li_a[jj];
      int wi=(li>=0)?li:(4096+li);
      if(wi>=0 && wi<4096) atomicMax(&mapping[wi], rank);
    }
  }
}

// ---------------------------------------------------------------------------
// Prep: gather (Hilbert + dilation) + fp32->f16 once (single-inst pkrtz),
// writing Kh/Vt in INVERSE-XOR-SWIZZLED 16B-slot order (unchanged layout).
//   Kh rows [row][d] (slot sl = d/8, swizzled by row&7).
//   Vt rows [d][k] per 64-row tile, K-INTERLEAVED slots: slot (4c+lg) holds
//   k = {32c+4lg+0..3, 32c+16+4lg+0..3}  -> PV B-frag is ONE 16B read.
// ---------------------------------------------------------------------------
__global__ __launch_bounds__(256) void prep_kv_kernel(
    const float* __restrict__ K, const float* __restrict__ V,
    const int* __restrict__ hmap,
    unsigned short* __restrict__ Kh, unsigned short* __restrict__ Vt)
{
  __shared__ unsigned short Vlds[64*72];
  const int bid = blockIdx.x, tid = threadIdx.x;
  int b, h, dstRowBase, srcRow;
  const int r = tid>>2, part = tid&3;
  if (bid < 1024){
    int t64 = bid&63; h = (bid>>6)&7; b = bid>>9;
    dstRowBase = (b*8+h)*4096 + t64*64;
    srcRow = t64*64 + r;
  } else {
    int bid2 = bid-1024;
    int t64 = bid2&31; int h8 = (bid2>>5)&7; b = bid2>>8; h = 8+h8;
    dstRowBase = G1ROWOFF + (b*8+h8)*2048 + t64*64;
    srcRow = 1 + 2*(t64*64 + r);
  }
  const int src = hmap[srcRow];
  const size_t sb = (((size_t)(b*N_+src))*H_ + h)*D_ + part*16;
  {
    const float4* kp = (const float4*)(K + sb);
    float4 a=kp[0], c=kp[1], e=kp[2], g=kp[3];
    uint4 w0, w1;
    w0.x=pkrtz(a.x,a.y); w0.y=pkrtz(a.z,a.w); w0.z=pkrtz(c.x,c.y); w0.w=pkrtz(c.z,c.w);
    w1.x=pkrtz(e.x,e.y); w1.y=pkrtz(e.z,e.w); w1.z=pkrtz(g.x,g.y); w1.w=pkrtz(g.z,g.w);
    char* dst = (char*)Kh + ((size_t)(dstRowBase+r))*128;
    *(uint4*)(dst + ((2*part  )^(r&7))*16) = w0;
    *(uint4*)(dst + ((2*part+1)^(r&7))*16) = w1;
  }
  {
    const float4* vp = (const float4*)(V + sb);
    float4 a=vp[0], c=vp[1], e=vp[2], g=vp[3];
    uint4 w0, w1;
    w0.x=pkrtz(a.x,a.y); w0.y=pkrtz(a.z,a.w); w0.z=pkrtz(c.x,c.y); w0.w=pkrtz(c.z,c.w);
    w1.x=pkrtz(e.x,e.y); w1.y=pkrtz(e.z,e.w); w1.z=pkrtz(g.x,g.y); w1.w=pkrtz(g.z,g.w);
    uint4* dst=(uint4*)&Vlds[r*72 + part*16];
    dst[0]=w0; dst[1]=w1;
  }
  __syncthreads();
  {
    const int d = tid>>2, p2 = tid&3;
    unsigned int w0[4], w1[4];
#pragma unroll
    for(int c=0;c<2;c++){
      int kb = 32*c + 4*p2;
      unsigned int* w = c ? w1 : w0;
      w[0] = pku(Vlds[(kb+ 0)*72+d], Vlds[(kb+ 1)*72+d]);
      w[1] = pku(Vlds[(kb+ 2)*72+d], Vlds[(kb+ 3)*72+d]);
      w[2] = pku(Vlds[(kb+16)*72+d], Vlds[(kb+17)*72+d]);
      w[3] = pku(Vlds[(kb+18)*72+d], Vlds[(kb+19)*72+d]);
    }
    char* dst = (char*)Vt + ((size_t)(dstRowBase+d))*128;
    *(uint4*)(dst + ((p2  )^(d&7))*16) = *(uint4*)w0;
    *(uint4*)(dst + ((p2+4)^(d&7))*16) = *(uint4*)w1;
  }
}

// ---------------------------------------------------------------------------
// Flash attention, f16, OCCUPANCY-FIRST: 1536 blocks x 256 thr (4 waves),
// 64 q-rows per block (16 per wave, ONE q-set). g1: 512 blocks x 32 tiles;
// g0: 1024 blocks x 16 tiles -> 6 blocks/CU nominal, 128 tile-units/CU.
// K staged in LDS (2 halves x 8KB -> 16KB/block); V read DIRECTLY from
// global (L2-resident panels; 5 waves/SIMD TLP hides the latency that round
// 11's 2 waves/SIMD could not). launch_bounds(256,5) caps VGPR ~102 so 5
// blocks/CU are resident. Per-FLOP LDS traffic identical to round 10.
// Single-tile rounds: vmcnt(0)[prev-round loads]+barrier+stageK(t+1)+
// V-issue+QK+SM+PV.
// ---------------------------------------------------------------------------
__global__ __launch_bounds__(256, 5) void dilated_attn_kernel(
    const float* __restrict__ Q, const unsigned short* __restrict__ Kh,
    const unsigned short* __restrict__ Vt, float* __restrict__ Out)
{
  __shared__ __align__(16) char smem[16384];   // 2 halves x 8KB (K only)

  const int bid = blockIdx.x, tid = threadIdx.x;
  const int wave = tid>>6, lane = tid&63;
  const int lr = lane&15, lg = lane>>4;

  int b, outH, qstep, qoff, nt, qloc;
  size_t kbase;
  if (bid < 512){                    // group 1: s=4096, r=2, off=1 (32 tiles)
    int xcd = bid&7, idx = bid>>3;   // idx 0..63
    int kblk = idx&31, Hp = idx>>5;
    int H = xcd + 8*Hp;              // panel 0..15; same panel -> same XCD
    b = H>>3; outH = 8 + (H&7);
    qstep = 2; qoff = 1; nt = 32;
    qloc = kblk*64;
    kbase = ((size_t)G1ROWOFF + (size_t)H*2048)*128;
    // zero the 64 paired even output rows (256 thr x 64B)
    int i = tid>>2, part = tid&3;
    int zpos = 2*(qloc + i);
    float4 z = {0.f,0.f,0.f,0.f};
    float4* op = (float4*)(Out + (((size_t)(b*N_+zpos))*H_ + outH)*D_ + part*16);
    op[0]=z; op[1]=z; op[2]=z; op[3]=z;
  } else {                           // group 0: s=1024, r=1 (16 tiles)
    int p = bid - 512;
    int xcd = p&7, idx = p>>3;       // idx 0..127
    int qb = idx&15, Gp = idx>>4;
    int G = xcd + 8*Gp;              // 0..63 = b*32+seg*8+h
    b = G>>5; int seg=(G>>3)&3; int h=G&7; outH=h;
    qstep = 1; qoff = 0; nt = 16;
    qloc = seg*1024 + qb*64;
    kbase = (((size_t)(b*8+h))*4096 + (size_t)seg*1024)*128;
  }

  // Q fragments (scale*log2e folded); one q-set of 16 rows per wave
  const float SCL = 0.125f * 1.4426950408889634f;
  f16x8 qf[2];
  {
    int qpos = qoff + qstep*(qloc + wave*16 + lr);
    const float* qp = Q + (((size_t)(b*N_+qpos))*H_ + outH)*D_;
#pragma unroll
    for(int dc=0;dc<2;dc++){
      float4 a = *(const float4*)(qp + dc*32 + lg*8);
      float4 c = *(const float4*)(qp + dc*32 + lg*8 + 4);
      union{ unsigned int u[4]; f16x8 v; } pk;
      pk.u[0]=pkrtz(a.x*SCL,a.y*SCL); pk.u[1]=pkrtz(a.z*SCL,a.w*SCL);
      pk.u[2]=pkrtz(c.x*SCL,c.y*SCL); pk.u[3]=pkrtz(c.z*SCL,c.w*SCL);
      qf[dc]=pk.v;
    }
  }

  f32x4 acc[4];
  f32x4 accl;
  const f32x4 FZ = {0.f,0.f,0.f,0.f};
#pragma unroll
  for(int dt=0;dt<4;dt++) acc[dt] = FZ;
  accl = FZ;
  union{ unsigned int u[4]; f16x8 v; } ONES;
  ONES.u[0]=0x3C003C00u; ONES.u[1]=0x3C003C00u; ONES.u[2]=0x3C003C00u; ONES.u[3]=0x3C003C00u;

  // read addresses (XOR-swizzled slots; same bytes as prep wrote)
  const int swz = lr&7;
  const int kA0 = lr*128 + ((  lg)^swz)*16;          // K frag, dc=0 (LDS)
  const int kA1 = lr*128 + ((4+lg)^swz)*16;          // K frag, dc=1 (LDS)
  const int vG0 = lr*128 + ((  lg)^swz)*16;          // V frag, c=0 (global, in-tile)
  const int vG1 = lr*128 + ((4+lg)^swz)*16;          // V frag, c=1

  // K staging: 8KB/tile, 256 thr x 32B (2 x 16B global_load_lds per thread)
  const int stW = wave*2048 + lane*16;
  auto stageK = [&](int bufOff, int t){
    const char* gsrc = (const char*)Kh + kbase + (size_t)t*8192 + stW;
    char* ldst = smem + bufOff + stW;
    __builtin_amdgcn_global_load_lds((const AS1 void*)(gsrc       ),
                                     (AS3 void*)(ldst       ), 16, 0, 0);
    __builtin_amdgcn_global_load_lds((const AS1 void*)(gsrc + 1024),
                                     (AS3 void*)(ldst + 1024), 16, 0, 0);
  };

  stageK(0, 0);
  for(int t=0; t<nt; ++t){
    asm volatile("s_waitcnt vmcnt(0)" ::: "memory");   // drain K-stage(t)
    __builtin_amdgcn_s_barrier();
    const int half = (t&1)*8192;
    if (t+1 < nt) stageK(((t+1)&1)*8192, t+1);

    // ---- issue V loads for tile t early (consumed at PV; latency hides
    //      under stage+QK+SM and cross-wave TLP)
    const char* gV = (const char*)Vt + kbase + (size_t)t*8192;
    uint4 vf[2][4];
#pragma unroll
    for(int c=0;c<2;c++){
      const int vGc = c ? vG1 : vG0;
#pragma unroll
      for(int dt=0;dt<4;dt++) vf[c][dt] = *(const uint4*)(gV + vGc + dt*2048);
    }

    // ---- QK: S^T = K.Q^T, lane holds S[k=16kt+4lg+rr][q=lr]; SM fused per kt
    const char* sm = smem + half;
    unsigned int U[4][2];
#pragma unroll
    for(int kt=0;kt<4;kt++){
      f16x8 k0 = *(const f16x8*)(sm + kA0 + kt*2048);
      f16x8 k1 = *(const f16x8*)(sm + kA1 + kt*2048);
      f32x4 s = __builtin_amdgcn_mfma_f32_16x16x32_f16(k0, qf[0], FZ, 0,0,0);
      s = __builtin_amdgcn_mfma_f32_16x16x32_f16(k1, qf[1], s, 0,0,0);
      U[kt][0] = pkrtz(__builtin_amdgcn_exp2f(s[0]), __builtin_amdgcn_exp2f(s[1]));
      U[kt][1] = pkrtz(__builtin_amdgcn_exp2f(s[2]), __builtin_amdgcn_exp2f(s[3]));
    }

    // ---- PV (+ l via ones-B MFMA)
#pragma unroll
    for(int c=0;c<2;c++){
      union{ unsigned int u[4]; f16x8 v; } pf;
      pf.u[0]=U[2*c][0]; pf.u[1]=U[2*c][1]; pf.u[2]=U[2*c+1][0]; pf.u[3]=U[2*c+1][1];
#pragma unroll
      for(int dt=0;dt<4;dt++){
        f16x8 vfr; __builtin_memcpy(&vfr, &vf[c][dt], 16);
        acc[dt] = __builtin_amdgcn_mfma_f32_16x16x32_f16(pf.v, vfr, acc[dt], 0,0,0);
      }
      accl = __builtin_amdgcn_mfma_f32_16x16x32_f16(pf.v, ONES.v, accl, 0,0,0);
    }
  }

  // ---- epilogue: rows q = lg*4+r, col d = dt*16+lr
#pragma unroll
  for(int r=0;r<4;r++){
    float inv = 1.0f/accl[r];
    int qpos = qoff + qstep*(qloc + wave*16 + lg*4 + r);
    float* op = Out + (((size_t)(b*N_+qpos))*H_ + outH)*D_ + lr;
#pragma unroll
    for(int dt=0;dt<4;dt++) op[dt*16] = acc[dt][r]*inv;
  }
}

extern "C" void kernel_launch(void* const* d_in, const int* in_sizes, int n_in,
                              void* d_out, int out_size, void* d_ws, size_t ws_size,
                              hipStream_t stream){
  const float* Q = (const float*)d_in[0];
  const float* K = (const float*)d_in[1];
  const float* V = (const float*)d_in[2];
  float* Out = (float*)d_out;

  int* hmap = (int*)d_ws;
  unsigned short* Kh = (unsigned short*)((char*)d_ws + 16384);
  unsigned short* Vt = (unsigned short*)((char*)d_ws + 16384 + 12582912);
  // ws usage: 16KB map + 2 x 12.6MB f16 tensors = ~25.2MB

  hipLaunchKernelGGL(hilbert_map_kernel, dim3(1), dim3(1024), 0, stream, hmap);
  hipLaunchKernelGGL(prep_kv_kernel, dim3(1536), dim3(256), 0, stream, K, V, hmap, Kh, Vt);
  hipLaunchKernelGGL(dilated_attn_kernel, dim3(1536), dim3(256), 0, stream, Q, Kh, Vt, Out);
}

// Round 13
// 68.844 us; speedup vs baseline: 1.2629x; 1.2629x over previous
//
#include <hip/hip_runtime.h>
#include <hip/hip_bf16.h>

#define N_ 4096
#define H_ 16
#define D_ 64
#define G1ROWOFF 65536  // row offset of group-1 region in Kh/Vt (2*8*4096 rows)

typedef __attribute__((ext_vector_type(4))) float f32x4;
typedef __attribute__((ext_vector_type(8))) _Float16 f16x8;

#define AS1 __attribute__((address_space(1)))
#define AS3 __attribute__((address_space(3)))

// Single-instruction pair convert f32x2 -> f16x2 (v_cvt_pkrtz_f16_f32).
__device__ __forceinline__ unsigned int pkrtz(float a, float b){
  auto h = __builtin_amdgcn_cvt_pkrtz(a, b);
  unsigned int r; __builtin_memcpy(&r, &h, 4); return r;
}
__device__ __forceinline__ unsigned int pku(unsigned int lo, unsigned int hi){
  return lo | (hi << 16);
}

// Un-sinkable 16B global load (saddr form): compiler cannot move volatile asm,
// so issue point == program point; completion gated by counted s_waitcnt vmcnt.
template<int IMM>
__device__ __forceinline__ uint4 gld16(const char* base, unsigned voff){
  uint4 r;
  if constexpr (IMM == 2048)
    asm volatile("global_load_dwordx4 %0, %1, %2 offset:2048"
                 : "=v"(r) : "v"(voff), "s"(base));
  else
    asm volatile("global_load_dwordx4 %0, %1, %2"
                 : "=v"(r) : "v"(voff), "s"(base));
  return r;
}

// ---------------------------------------------------------------------------
// Hilbert mapping (exact replica of reference incl. its quirks).
// ---------------------------------------------------------------------------
__global__ __launch_bounds__(1024) void hilbert_map_kernel(int* __restrict__ mapping){
  __shared__ int sm[4096];
  const int t = threadIdx.x;
#pragma unroll
  for(int jj=0;jj<4;jj++) mapping[t*4+jj] = 0;   // np.zeros default
  int li_a[4], val_a[4];
#pragma unroll
  for(int jj=0;jj<4;jj++){
    int i = t*4+jj;
    int x=0,y=0,d=i;
#pragma unroll
    for(int s=1;s<64;s<<=1){
      int rx=(d>>1)&1;
      int ry=(d^rx)&1;
      if(ry==0){
        if(rx==1){ x=63-x; y=63-y; }   // nn-1-x reflection (reference quirk)
        int tp=x; x=y; y=tp;
      }
      x+=s*rx; y+=s*ry;
      d>>=2;
    }
    int li=y*64+x;
    li_a[jj]=li;
    val_a[jj]=(li<4096)?1:0;
    sm[i]=val_a[jj];
  }
  __syncthreads();
  for(int off=1;off<4096;off<<=1){
    int v[4];
#pragma unroll
    for(int jj=0;jj<4;jj++){
      int i=t*4+jj;
      v[jj]=sm[i]+((i>=off)?sm[i-off]:0);
    }
    __syncthreads();
#pragma unroll
    for(int jj=0;jj<4;jj++) sm[t*4+jj]=v[jj];
    __syncthreads();
  }
#pragma unroll
  for(int jj=0;jj<4;jj++){
    if(val_a[jj]){
      int rank=sm[t*4+jj]-1;
      int li=li_a[jj];
      int wi=(li>=0)?li:(4096+li);
      if(wi>=0 && wi<4096) atomicMax(&mapping[wi], rank);
    }
  }
}

// ---------------------------------------------------------------------------
// Prep: gather (Hilbert + dilation) + fp32->f16 once (single-inst pkrtz),
// writing Kh/Vt in INVERSE-XOR-SWIZZLED 16B-slot order.
//   Kh rows [row][d] (slot sl = d/8, swizzled by row&7).
//   Vt rows [d][k] per 64-row tile, K-INTERLEAVED slots: slot (4c+lg) holds
//   k = {32c+4lg+0..3, 32c+16+4lg+0..3}  -> PV B-frag is ONE 16B read.
// ---------------------------------------------------------------------------
__global__ __launch_bounds__(256) void prep_kv_kernel(
    const float* __restrict__ K, const float* __restrict__ V,
    const int* __restrict__ hmap,
    unsigned short* __restrict__ Kh, unsigned short* __restrict__ Vt)
{
  __shared__ unsigned short Vlds[64*72];
  const int bid = blockIdx.x, tid = threadIdx.x;
  int b, h, dstRowBase, srcRow;
  const int r = tid>>2, part = tid&3;
  if (bid < 1024){
    int t64 = bid&63; h = (bid>>6)&7; b = bid>>9;
    dstRowBase = (b*8+h)*4096 + t64*64;
    srcRow = t64*64 + r;
  } else {
    int bid2 = bid-1024;
    int t64 = bid2&31; int h8 = (bid2>>5)&7; b = bid2>>8; h = 8+h8;
    dstRowBase = G1ROWOFF + (b*8+h8)*2048 + t64*64;
    srcRow = 1 + 2*(t64*64 + r);
  }
  const int src = hmap[srcRow];
  const size_t sb = (((size_t)(b*N_+src))*H_ + h)*D_ + part*16;
  {
    const float4* kp = (const float4*)(K + sb);
    float4 a=kp[0], c=kp[1], e=kp[2], g=kp[3];
    uint4 w0, w1;
    w0.x=pkrtz(a.x,a.y); w0.y=pkrtz(a.z,a.w); w0.z=pkrtz(c.x,c.y); w0.w=pkrtz(c.z,c.w);
    w1.x=pkrtz(e.x,e.y); w1.y=pkrtz(e.z,e.w); w1.z=pkrtz(g.x,g.y); w1.w=pkrtz(g.z,g.w);
    char* dst = (char*)Kh + ((size_t)(dstRowBase+r))*128;
    *(uint4*)(dst + ((2*part  )^(r&7))*16) = w0;
    *(uint4*)(dst + ((2*part+1)^(r&7))*16) = w1;
  }
  {
    const float4* vp = (const float4*)(V + sb);
    float4 a=vp[0], c=vp[1], e=vp[2], g=vp[3];
    uint4 w0, w1;
    w0.x=pkrtz(a.x,a.y); w0.y=pkrtz(a.z,a.w); w0.z=pkrtz(c.x,c.y); w0.w=pkrtz(c.z,c.w);
    w1.x=pkrtz(e.x,e.y); w1.y=pkrtz(e.z,e.w); w1.z=pkrtz(g.x,g.y); w1.w=pkrtz(g.z,g.w);
    uint4* dst=(uint4*)&Vlds[r*72 + part*16];
    dst[0]=w0; dst[1]=w1;
  }
  __syncthreads();
  {
    const int d = tid>>2, p2 = tid&3;
    unsigned int w0[4], w1[4];
#pragma unroll
    for(int c=0;c<2;c++){
      int kb = 32*c + 4*p2;
      unsigned int* w = c ? w1 : w0;
      w[0] = pku(Vlds[(kb+ 0)*72+d], Vlds[(kb+ 1)*72+d]);
      w[1] = pku(Vlds[(kb+ 2)*72+d], Vlds[(kb+ 3)*72+d]);
      w[2] = pku(Vlds[(kb+16)*72+d], Vlds[(kb+17)*72+d]);
      w[3] = pku(Vlds[(kb+18)*72+d], Vlds[(kb+19)*72+d]);
    }
    char* dst = (char*)Vt + ((size_t)(dstRowBase+d))*128;
    *(uint4*)(dst + ((p2  )^(d&7))*16) = *(uint4*)w0;
    *(uint4*)(dst + ((p2+4)^(d&7))*16) = *(uint4*)w1;
  }
}

// ---------------------------------------------------------------------------
// Flash attention, f16. Round-10 structure (best: 51us attn) + V moved from
// LDS to REGISTERS via volatile-asm loads + counted vmcnt (T4/T14):
//   512 uniform blocks x 256 thr (4 waves), 128q/block, 16 two-tile rounds.
//   K: LDS double-buffered (2 halves x 2 tiles x 8KB = 32KB), global_load_lds.
//   V: 16 asm global_load_dwordx4 issued at round top (cannot be sunk),
//      order-pinned [V-A(8), V-B(8), stageK(4)] via sched_barrier(0);
//      PV_A waits vmcnt(12) (V-A done, V-B+stage in flight);
//      PV_B waits vmcnt(4)  (V-B done, stage in flight -> drained next top).
// Removes ~half of r10's LDS traffic (the dominant pipe) without r11's
// latency exposure (loads covered by a full QK+SM phase).
// ---------------------------------------------------------------------------
__global__ __launch_bounds__(256, 2) void dilated_attn_kernel(
    const float* __restrict__ Q, const unsigned short* __restrict__ Kh,
    const unsigned short* __restrict__ Vt, float* __restrict__ Out)
{
  __shared__ __align__(16) char smem[32768];   // 2 halves x 2 tiles x 8KB (K)

  const int bid = blockIdx.x, tid = threadIdx.x;
  const int wave = tid>>6, lane = tid&63;
  const int lr = lane&15, lg = lane>>4;

  int b, outH, qstep, qoff, njobs, nrj;
  int qloc[2];
  size_t kb0, kb1;    // byte offsets of the two 16-tile KV half-ranges
  if (bid < 256){                    // group 1: s=4096, r=2, off=1
    int xcd = bid&7, idx = bid>>3;
    int kblk = idx&15, Hp = idx>>4;
    int H = xcd + 8*Hp;              // panel; blocks of same panel share XCD
    b = H>>3; outH = 8 + (H&7);
    qstep = 2; qoff = 1; njobs = 1; nrj = 16;
    qloc[0] = kblk*128; qloc[1] = qloc[0];
    size_t rowBase = (size_t)G1ROWOFF + (size_t)H*2048;
    kb0 = rowBase*128; kb1 = kb0 + 16*8192;
    // zero the 128 paired even output rows (256 thr x 128B)
    int i = tid>>1, half = tid&1;
    int zpos = 2*(qloc[0] + i);
    float4 z = {0.f,0.f,0.f,0.f};
    float4* op = (float4*)(Out + (((size_t)(b*N_+zpos))*H_ + outH)*D_ + half*32);
#pragma unroll
    for(int j=0;j<8;j++) op[j]=z;
  } else {                           // group 0: s=1024, r=1 (2 jobs, shared KV)
    int p = bid - 256;
    int xcd = p&7, idx = p>>3;
    int pair = idx&3, Gp = idx>>2;
    int G = xcd + 8*Gp;              // G = b*32+seg*8+h
    b = G>>5; int seg=(G>>3)&3; int h=G&7; outH=h;
    qstep = 1; qoff = 0; njobs = 2; nrj = 8;
    qloc[0] = seg*1024 + pair*128;
    qloc[1] = seg*1024 + (pair+4)*128;
    size_t rowBase = ((size_t)(b*8+h))*4096 + (size_t)seg*1024;
    kb0 = rowBase*128; kb1 = kb0;    // both jobs read the same panel
  }

  const float SCL = 0.125f * 1.4426950408889634f;
  f16x8 qf[2][2];
  f32x4 acc[2][4];
  f32x4 accl[2];
  const f32x4 FZ = {0.f,0.f,0.f,0.f};
  union{ unsigned int u[4]; f16x8 v; } ONES;
  ONES.u[0]=0x3C003C00u; ONES.u[1]=0x3C003C00u; ONES.u[2]=0x3C003C00u; ONES.u[3]=0x3C003C00u;

  auto loadQ = [&](int ql0){
#pragma unroll
    for(int qs=0;qs<2;qs++){
      int qpos = qoff + qstep*(ql0 + wave*32 + qs*16 + lr);
      const float* qp = Q + (((size_t)(b*N_+qpos))*H_ + outH)*D_;
#pragma unroll
      for(int dc=0;dc<2;dc++){
        float4 a = *(const float4*)(qp + dc*32 + lg*8);
        float4 c = *(const float4*)(qp + dc*32 + lg*8 + 4);
        union{ unsigned int u[4]; f16x8 v; } pk;
        pk.u[0]=pkrtz(a.x*SCL,a.y*SCL); pk.u[1]=pkrtz(a.z*SCL,a.w*SCL);
        pk.u[2]=pkrtz(c.x*SCL,c.y*SCL); pk.u[3]=pkrtz(c.z*SCL,c.w*SCL);
        qf[qs][dc]=pk.v;
      }
    }
  };

  // read addresses (XOR-swizzled slots; same bytes as prep wrote)
  const int swz = lr&7;
  const int kA0 = lr*128 + ((  lg)^swz)*16;          // K frag, dc=0 (LDS)
  const int kA1 = lr*128 + ((4+lg)^swz)*16;          // K frag, dc=1 (LDS)
  const unsigned vG0 = (unsigned)(lr*128 + ((  lg)^swz)*16);  // V frag voffs
  const unsigned vG1 = (unsigned)(lr*128 + ((4+lg)^swz)*16);

  // K staging: 8KB/tile, per thread 2 x 16B (wave-uniform base + lane*16)
  const int stW = wave*2048 + lane*16;
  auto stageK = [&](int bufOff, int t){
    size_t off = ((t>=16)? kb1 : kb0) + (size_t)(t&15)*8192 + stW;
    const char* gsrc = (const char*)Kh + off;
    char* ldst = smem + bufOff + stW;
    __builtin_amdgcn_global_load_lds((const AS1 void*)(gsrc       ),
                                     (AS3 void*)(ldst       ), 16, 0, 0);
    __builtin_amdgcn_global_load_lds((const AS1 void*)(gsrc + 1024),
                                     (AS3 void*)(ldst + 1024), 16, 0, 0);
  };

  auto epilogue = [&](int ql0){
#pragma unroll
    for(int qs=0;qs<2;qs++)
#pragma unroll
      for(int r=0;r<4;r++){
        float inv = 1.0f/accl[qs][r];
        int qpos = qoff + qstep*(ql0 + wave*32 + qs*16 + lg*4 + r);
        float* op = Out + (((size_t)(b*N_+qpos))*H_ + outH)*D_ + lr;
#pragma unroll
        for(int dt=0;dt<4;dt++) op[dt*16] = acc[qs][dt][r]*inv;
      }
  };

  // Pair-round pipeline; K loads for pair p+1 issued inside round p.
  stageK(0, 0); stageK(8192, 1);     // pair 0 -> half 0
  int p = 0;
  for(int j=0; j<njobs; ++j){
    loadQ(qloc[j]);
#pragma unroll
    for(int qs=0;qs<2;qs++){
#pragma unroll
      for(int dt=0;dt<4;dt++) acc[qs][dt] = FZ;
      accl[qs] = FZ;
    }
    for(int r=0; r<nrj; ++r, ++p){
      asm volatile("s_waitcnt vmcnt(0)" ::: "memory");   // drain prev stage
      __builtin_amdgcn_s_barrier();
      const int half = (p&1)*16384;
      const int oth  = ((p+1)&1)*16384;

      // ---- issue V loads for BOTH tiles (volatile asm: cannot be sunk)
      const int tA = 2*p, tB = 2*p+1;
      const char* gVA = (const char*)Vt + ((tA>=16)? kb1 : kb0) + (size_t)(tA&15)*8192;
      const char* gVB = (const char*)Vt + ((tB>=16)? kb1 : kb0) + (size_t)(tB&15)*8192;
      uint4 vfA[2][4], vfB[2][4];
#pragma unroll
      for(int c=0;c<2;c++){
        const unsigned voffc = c ? vG1 : vG0;
        vfA[c][0]=gld16<0>(gVA, voffc);        vfA[c][1]=gld16<2048>(gVA, voffc);
        vfA[c][2]=gld16<0>(gVA+4096, voffc);   vfA[c][3]=gld16<2048>(gVA+4096, voffc);
      }
#pragma unroll
      for(int c=0;c<2;c++){
        const unsigned voffc = c ? vG1 : vG0;
        vfB[c][0]=gld16<0>(gVB, voffc);        vfB[c][1]=gld16<2048>(gVB, voffc);
        vfB[c][2]=gld16<0>(gVB+4096, voffc);   vfB[c][3]=gld16<2048>(gVB+4096, voffc);
      }
      __builtin_amdgcn_sched_barrier(0);
      // ---- stage K pair p+1 (dummy re-stage at p=15 keeps vmcnt uniform)
      stageK(oth, 2*p+2); stageK(oth+8192, 2*p+3);
      __builtin_amdgcn_sched_barrier(0);

      const char* smA = smem + half;
      const char* smB = smem + half + 8192;

      // ---- QK_A: S^T = K.Q^T, lane holds S[k=16kt+4lg+rr][q=lr]
      f32x4 sA[2][4], sB[2][4];
#pragma unroll
      for(int kt=0;kt<4;kt++){
        f16x8 k0 = *(const f16x8*)(smA + kA0 + kt*2048);
        f16x8 k1 = *(const f16x8*)(smA + kA1 + kt*2048);
#pragma unroll
        for(int qs=0;qs<2;qs++){
          sA[qs][kt] = __builtin_amdgcn_mfma_f32_16x16x32_f16(k0, qf[qs][0], FZ, 0,0,0);
          sA[qs][kt] = __builtin_amdgcn_mfma_f32_16x16x32_f16(k1, qf[qs][1], sA[qs][kt],0,0,0);
        }
      }

      // ---- QK_B with SM_A fused per kt (MFMA || exp2/pkrtz co-issue)
      unsigned int UA[2][4][2], UB[2][4][2];
#pragma unroll
      for(int kt=0;kt<4;kt++){
        f16x8 k0 = *(const f16x8*)(smB + kA0 + kt*2048);
        f16x8 k1 = *(const f16x8*)(smB + kA1 + kt*2048);
        sB[0][kt] = __builtin_amdgcn_mfma_f32_16x16x32_f16(k0, qf[0][0], FZ, 0,0,0);
        UA[0][kt][0] = pkrtz(__builtin_amdgcn_exp2f(sA[0][kt][0]),
                             __builtin_amdgcn_exp2f(sA[0][kt][1]));
        sB[0][kt] = __builtin_amdgcn_mfma_f32_16x16x32_f16(k1, qf[0][1], sB[0][kt],0,0,0);
        UA[0][kt][1] = pkrtz(__builtin_amdgcn_exp2f(sA[0][kt][2]),
                             __builtin_amdgcn_exp2f(sA[0][kt][3]));
        sB[1][kt] = __builtin_amdgcn_mfma_f32_16x16x32_f16(k0, qf[1][0], FZ, 0,0,0);
        UA[1][kt][0] = pkrtz(__builtin_amdgcn_exp2f(sA[1][kt][0]),
                             __builtin_amdgcn_exp2f(sA[1][kt][1]));
        sB[1][kt] = __builtin_amdgcn_mfma_f32_16x16x32_f16(k1, qf[1][1], sB[1][kt],0,0,0);
        UA[1][kt][1] = pkrtz(__builtin_amdgcn_exp2f(sA[1][kt][2]),
                             __builtin_amdgcn_exp2f(sA[1][kt][3]));
      }
      union{ unsigned int u[4]; f16x8 v; } pfA[2][2];
#pragma unroll
      for(int qs=0;qs<2;qs++)
#pragma unroll
        for(int c=0;c<2;c++){
          pfA[qs][c].u[0]=UA[qs][2*c][0]; pfA[qs][c].u[1]=UA[qs][2*c][1];
          pfA[qs][c].u[2]=UA[qs][2*c+1][0]; pfA[qs][c].u[3]=UA[qs][2*c+1][1];
        }

      // ---- PV_A with SM_B fused; V-A regs valid after vmcnt(12)
      asm volatile("s_waitcnt vmcnt(12)" ::: "memory");
      __builtin_amdgcn_sched_barrier(0);
#pragma unroll
      for(int c=0;c<2;c++){
#pragma unroll
        for(int dt=0;dt<4;dt++){
          f16x8 vf; __builtin_memcpy(&vf, &vfA[c][dt], 16);
          const int bqs = dt>>1, bkt = 2*c + (dt&1);
          acc[0][dt] = __builtin_amdgcn_mfma_f32_16x16x32_f16(pfA[0][c].v, vf, acc[0][dt],0,0,0);
          UB[bqs][bkt][0] = pkrtz(__builtin_amdgcn_exp2f(sB[bqs][bkt][0]),
                                  __builtin_amdgcn_exp2f(sB[bqs][bkt][1]));
          acc[1][dt] = __builtin_amdgcn_mfma_f32_16x16x32_f16(pfA[1][c].v, vf, acc[1][dt],0,0,0);
          UB[bqs][bkt][1] = pkrtz(__builtin_amdgcn_exp2f(sB[bqs][bkt][2]),
                                  __builtin_amdgcn_exp2f(sB[bqs][bkt][3]));
        }
        accl[0] = __builtin_amdgcn_mfma_f32_16x16x32_f16(pfA[0][c].v, ONES.v, accl[0],0,0,0);
        accl[1] = __builtin_amdgcn_mfma_f32_16x16x32_f16(pfA[1][c].v, ONES.v, accl[1],0,0,0);
      }

      // ---- PV_B; V-B regs valid after vmcnt(4) (stage stays in flight)
      asm volatile("s_waitcnt vmcnt(4)" ::: "memory");
      __builtin_amdgcn_sched_barrier(0);
#pragma unroll
      for(int c=0;c<2;c++){
        union{ unsigned int u[4]; f16x8 v; } pf0, pf1;
        pf0.u[0]=UB[0][2*c][0]; pf0.u[1]=UB[0][2*c][1]; pf0.u[2]=UB[0][2*c+1][0]; pf0.u[3]=UB[0][2*c+1][1];
        pf1.u[0]=UB[1][2*c][0]; pf1.u[1]=UB[1][2*c][1]; pf1.u[2]=UB[1][2*c+1][0]; pf1.u[3]=UB[1][2*c+1][1];
#pragma unroll
        for(int dt=0;dt<4;dt++){
          f16x8 vf; __builtin_memcpy(&vf, &vfB[c][dt], 16);
          acc[0][dt] = __builtin_amdgcn_mfma_f32_16x16x32_f16(pf0.v, vf, acc[0][dt],0,0,0);
          acc[1][dt] = __builtin_amdgcn_mfma_f32_16x16x32_f16(pf1.v, vf, acc[1][dt],0,0,0);
        }
        accl[0] = __builtin_amdgcn_mfma_f32_16x16x32_f16(pf0.v, ONES.v, accl[0],0,0,0);
        accl[1] = __builtin_amdgcn_mfma_f32_16x16x32_f16(pf1.v, ONES.v, accl[1],0,0,0);
      }
    }
    epilogue(qloc[j]);               // registers+global only: no barrier needed
  }
}

extern "C" void kernel_launch(void* const* d_in, const int* in_sizes, int n_in,
                              void* d_out, int out_size, void* d_ws, size_t ws_size,
                              hipStream_t stream){
  const float* Q = (const float*)d_in[0];
  const float* K = (const float*)d_in[1];
  const float* V = (const float*)d_in[2];
  float* Out = (float*)d_out;

  int* hmap = (int*)d_ws;
  unsigned short* Kh = (unsigned short*)((char*)d_ws + 16384);
  unsigned short* Vt = (unsigned short*)((char*)d_ws + 16384 + 12582912);
  // ws usage: 16KB map + 2 x 12.6MB f16 tensors = ~25.2MB

  hipLaunchKernelGGL(hilbert_map_kernel, dim3(1), dim3(1024), 0, stream, hmap);
  hipLaunchKernelGGL(prep_kv_kernel, dim3(1536), dim3(256), 0, stream, K, V, hmap, Kh, Vt);
  hipLaunchKernelGGL(dilated_attn_kernel, dim3(512), dim3(256), 0, stream, Q, Kh, Vt, Out);
}